// Round 1
// baseline (75.659 us; speedup 1.0000x reference)
//
#include <hip/hip_runtime.h>
#include <math.h>

#define NN 4096

// sig2 exactly as reference: sig = sqrt(-2/log(1-avg^2)); sig2 = sig*sig
__device__ __forceinline__ float sig2_of_sum(float s) {
    float avg = s / 200.0f;
    float v = -2.0f / logf(1.0f - avg * avg);
    float sg = sqrtf(v);
    return sg * sg;
}

// ws layout (as float*/int* aliased):
//  f[0]=begin  f[1]=interval  f[2]=sum_sig2  f[3]=sum_tr2
//  i[4]=cnt    i[5]=K (candidate count)      i[8..8+4095]=candidate indices

__global__ void ENCELDDT_kA(const float* __restrict__ sigmas,
                            float* __restrict__ wsf, int* __restrict__ wsi,
                            int* __restrict__ cand) {
    __shared__ float sm1[256], sm2[256], sM1[256], sM2[256];
    const int t = threadIdx.x;

    float m1 = INFINITY, m2 = INFINITY, M1 = -INFINITY, M2 = -INFINITY;
    for (int i = t; i < NN; i += 256) {
        float v = sigmas[i];
        if (v < m1) { m2 = m1; m1 = v; } else if (v < m2) { m2 = v; }
        if (v > M1) { M2 = M1; M1 = v; } else if (v > M2) { M2 = v; }
    }
    sm1[t] = m1; sm2[t] = m2; sM1[t] = M1; sM2[t] = M2;
    __syncthreads();

    for (int off = 128; off > 0; off >>= 1) {
        if (t < off) {
            float b1 = sm1[t], b2 = sm2[t];
            float v = sm1[t + off];
            if (v < b1) { b2 = b1; b1 = v; } else if (v < b2) { b2 = v; }
            v = sm2[t + off];
            if (v < b1) { b2 = b1; b1 = v; } else if (v < b2) { b2 = v; }
            sm1[t] = b1; sm2[t] = b2;

            float c1 = sM1[t], c2 = sM2[t];
            v = sM1[t + off];
            if (v > c1) { c2 = c1; c1 = v; } else if (v > c2) { c2 = v; }
            v = sM2[t + off];
            if (v > c1) { c2 = c1; c1 = v; } else if (v > c2) { c2 = v; }
            sM1[t] = c1; sM2[t] = c2;
        }
        __syncthreads();
    }

    m1 = sm1[0]; m2 = sm2[0]; M1 = sM1[0]; M2 = sM2[0];

    const float begin    = sig2_of_sum(M1 + M2);   // min of sig2 (sig2 decreasing in sum)
    const float endv     = sig2_of_sum(m1 + m2);   // max of sig2
    const float interval = (endv - begin) / 10.0f;

    if (t == 0) {
        wsf[0] = begin;
        wsf[1] = interval;
        wsf[2] = 0.0f;     // sum_sig2
        wsf[3] = 0.0f;     // sum_tr2
        wsi[4] = 0;        // cnt
        wsi[5] = 0;        // K
    }
    __syncthreads();

    // Candidate scan: i can be in a bin-9 pair only if its BEST possible partner
    // (the global min sigma m1) would put it in bin 9 (with float-rounding slack).
    // Exact membership is re-tested per-pair in kernel B, so superset is safe.
    for (int i = t; i < NN; i += 256) {
        float s = sigmas[i];
        float x = (sig2_of_sum(s + m1) - begin) / interval;
        if (x >= 9.0f - 1e-3f) {
            int k = atomicAdd(wsi + 5, 1);
            cand[k] = i;
        }
    }
}

__global__ void ENCELDDT_kB(const float* __restrict__ sigmas,
                            const float* __restrict__ y,
                            const float* __restrict__ py,
                            float* __restrict__ wsf, int* __restrict__ wsi,
                            const int* __restrict__ cand) {
    const float begin    = wsf[0];
    const float interval = wsf[1];
    const int   K        = wsi[5];

    float ssig2 = 0.0f, str2 = 0.0f;
    int cnt = 0;

    const long long total  = (long long)K * (long long)K;
    const long long stride = (long long)gridDim.x * blockDim.x;
    for (long long idx = (long long)blockIdx.x * blockDim.x + threadIdx.x;
         idx < total; idx += stride) {
        int a = (int)(idx / K);
        int b = (int)(idx - (long long)a * K);
        if (a == b) continue;           // off-diagonal: i != j
        int i = cand[a];
        int j = cand[b];

        float s2 = sig2_of_sum(sigmas[i] + sigmas[j]);
        float x  = (s2 - begin) / interval;
        // bin index = clip(floor(x),0,9); membership in bin 9 <=> x >= 9.0f
        if (x >= 9.0f) {
            float dx = y[3 * i]     - y[3 * j];
            float dy = y[3 * i + 1] - y[3 * j + 1];
            float dz = y[3 * i + 2] - y[3 * j + 2];
            float dgt = sqrtf((dx * dx + dy * dy) + dz * dz);
            dx = py[3 * i]     - py[3 * j];
            dy = py[3 * i + 1] - py[3 * j + 1];
            dz = py[3 * i + 2] - py[3 * j + 2];
            float dpd = sqrtf((dx * dx + dy * dy) + dz * dz);
            float tr = dgt - dpd;
            ssig2 += s2;
            str2  += tr * tr;
            cnt   += 1;
        }
    }

    __shared__ float r1[256];
    __shared__ float r2[256];
    __shared__ int   r3[256];
    const int t = threadIdx.x;
    r1[t] = ssig2; r2[t] = str2; r3[t] = cnt;
    __syncthreads();
    for (int off = 128; off > 0; off >>= 1) {
        if (t < off) {
            r1[t] += r1[t + off];
            r2[t] += r2[t + off];
            r3[t] += r3[t + off];
        }
        __syncthreads();
    }
    if (t == 0 && r3[0] > 0) {
        atomicAdd(wsf + 2, r1[0]);
        atomicAdd(wsf + 3, r2[0]);
        atomicAdd(wsi + 4, r3[0]);
    }
}

__global__ void ENCELDDT_kC(const float* __restrict__ wsf,
                            const int* __restrict__ wsi,
                            float* __restrict__ out) {
    float cnt  = (float)wsi[4];
    float mvar = sqrtf(wsf[2] / cnt);
    float rmse = sqrtf(wsf[3] / cnt);
    out[0] = fabsf(mvar - rmse) / mvar;
}

extern "C" void kernel_launch(void* const* d_in, const int* in_sizes, int n_in,
                              void* d_out, int out_size, void* d_ws, size_t ws_size,
                              hipStream_t stream) {
    const float* sigmas = (const float*)d_in[0];
    const float* y      = (const float*)d_in[1];
    const float* py     = (const float*)d_in[2];
    float* out = (float*)d_out;

    float* wsf = (float*)d_ws;
    int*   wsi = (int*)d_ws;
    int*   cand = wsi + 8;

    ENCELDDT_kA<<<1, 256, 0, stream>>>(sigmas, wsf, wsi, cand);
    ENCELDDT_kB<<<64, 256, 0, stream>>>(sigmas, y, py, wsf, wsi, cand);
    ENCELDDT_kC<<<1, 1, 0, stream>>>(wsf, wsi, out);
}

// Round 2
// 70.431 us; speedup vs baseline: 1.0742x; 1.0742x over previous
//
#include <hip/hip_runtime.h>
#include <math.h>

#define NN 4096
#define MAXC 2048   // candidate cap (expected K ~ 5; conservative superset)

// sig2 exactly as reference: sig = sqrt(-2/log(1-avg^2)); sig2 = sig*sig
__device__ __forceinline__ float sig2_of_sum(float s) {
    float avg = s / 200.0f;
    float v = -2.0f / logf(1.0f - avg * avg);
    float sg = sqrtf(v);
    return sg * sg;
}

__global__ __launch_bounds__(256) void ENCELDDT_fused(
        const float* __restrict__ sigmas,
        const float* __restrict__ y,
        const float* __restrict__ py,
        float* __restrict__ out) {
    __shared__ float sm1[256], sm2[256], sM1[256], sM2[256];
    __shared__ float r1[256], r2[256];
    __shared__ int   r3[256];
    __shared__ int   s_cand[MAXC];
    __shared__ int   s_K;

    const int t = threadIdx.x;
    if (t == 0) s_K = 0;

    // ---- Phase 1: two-min / two-max of sigmas ----
    float m1 = INFINITY, m2 = INFINITY, M1 = -INFINITY, M2 = -INFINITY;
    for (int i = t; i < NN; i += 256) {
        float v = sigmas[i];
        if (v < m1) { m2 = m1; m1 = v; } else if (v < m2) { m2 = v; }
        if (v > M1) { M2 = M1; M1 = v; } else if (v > M2) { M2 = v; }
    }
    sm1[t] = m1; sm2[t] = m2; sM1[t] = M1; sM2[t] = M2;
    __syncthreads();

    for (int off = 128; off > 0; off >>= 1) {
        if (t < off) {
            float b1 = sm1[t], b2 = sm2[t];
            float v = sm1[t + off];
            if (v < b1) { b2 = b1; b1 = v; } else if (v < b2) { b2 = v; }
            v = sm2[t + off];
            if (v < b1) { b2 = b1; b1 = v; } else if (v < b2) { b2 = v; }
            sm1[t] = b1; sm2[t] = b2;

            float c1 = sM1[t], c2 = sM2[t];
            v = sM1[t + off];
            if (v > c1) { c2 = c1; c1 = v; } else if (v > c2) { c2 = v; }
            v = sM2[t + off];
            if (v > c1) { c2 = c1; c1 = v; } else if (v > c2) { c2 = v; }
            sM1[t] = c1; sM2[t] = c2;
        }
        __syncthreads();
    }

    m1 = sm1[0]; m2 = sm2[0]; M1 = sM1[0]; M2 = sM2[0];

    // sig2 is strictly decreasing in the sigma sum:
    const float begin    = sig2_of_sum(M1 + M2);   // min of sig2
    const float endv     = sig2_of_sum(m1 + m2);   // max of sig2
    const float interval = (endv - begin) / 10.0f;

    // ---- Phase 2: candidate scan ----
    // i can belong to a bin-9 pair only if pairing with the global-min sigma
    // would reach bin 9 (with slack). Exact membership re-tested per pair.
    for (int i = t; i < NN; i += 256) {
        float x = (sig2_of_sum(sigmas[i] + m1) - begin) / interval;
        if (x >= 9.0f - 1e-3f) {
            int k = atomicAdd(&s_K, 1);
            if (k < MAXC) s_cand[k] = i;
        }
    }
    __syncthreads();

    const int K = (s_K < MAXC) ? s_K : MAXC;

    // ---- Phase 3: exact pair loop over K*K ordered pairs ----
    float ssig2 = 0.0f, str2 = 0.0f;
    int cnt = 0;
    const int total = K * K;
    for (int idx = t; idx < total; idx += 256) {
        int a = idx / K;
        int b = idx - a * K;
        if (a == b) continue;          // off-diagonal: i != j
        int i = s_cand[a];
        int j = s_cand[b];

        float s2 = sig2_of_sum(sigmas[i] + sigmas[j]);
        float x  = (s2 - begin) / interval;
        // bin = clip(floor(x),0,9); membership in bin 9 <=> x >= 9.0f
        if (x >= 9.0f) {
            float dx = y[3 * i]     - y[3 * j];
            float dy = y[3 * i + 1] - y[3 * j + 1];
            float dz = y[3 * i + 2] - y[3 * j + 2];
            float dgt = sqrtf((dx * dx + dy * dy) + dz * dz);
            dx = py[3 * i]     - py[3 * j];
            dy = py[3 * i + 1] - py[3 * j + 1];
            dz = py[3 * i + 2] - py[3 * j + 2];
            float dpd = sqrtf((dx * dx + dy * dy) + dz * dz);
            float tr = dgt - dpd;
            ssig2 += s2;
            str2  += tr * tr;
            cnt   += 1;
        }
    }

    r1[t] = ssig2; r2[t] = str2; r3[t] = cnt;
    __syncthreads();
    for (int off = 128; off > 0; off >>= 1) {
        if (t < off) {
            r1[t] += r1[t + off];
            r2[t] += r2[t + off];
            r3[t] += r3[t + off];
        }
        __syncthreads();
    }

    // ---- Phase 4: final scalar ----
    if (t == 0) {
        float c    = (float)r3[0];
        float mvar = sqrtf(r1[0] / c);
        float rmse = sqrtf(r2[0] / c);
        out[0] = fabsf(mvar - rmse) / mvar;
    }
}

extern "C" void kernel_launch(void* const* d_in, const int* in_sizes, int n_in,
                              void* d_out, int out_size, void* d_ws, size_t ws_size,
                              hipStream_t stream) {
    const float* sigmas = (const float*)d_in[0];
    const float* y      = (const float*)d_in[1];
    const float* py     = (const float*)d_in[2];
    float* out = (float*)d_out;

    ENCELDDT_fused<<<1, 256, 0, stream>>>(sigmas, y, py, out);
}

// Round 3
// 60.963 us; speedup vs baseline: 1.2411x; 1.1553x over previous
//
#include <hip/hip_runtime.h>
#include <math.h>

#define NN 4096
#define NT 1024          // threads; NT*4 == NN exactly
#define NWAVE (NT / 64)  // 16 waves
#define MAXC 1024        // candidate cap (expected K ~ 3-6; conservative)

// sig2 exactly as reference: sig = sqrt(-2/log(1-avg^2)); sig2 = sig*sig
__device__ __forceinline__ float sig2_of_sum(float s) {
    float avg = s / 200.0f;
    float v = -2.0f / logf(1.0f - avg * avg);
    float sg = sqrtf(v);
    return sg * sg;
}

// merge (b1,b2) two-smallest into (a1,a2)
__device__ __forceinline__ void merge2min(float& a1, float& a2, float b1, float b2) {
    float lo = fminf(a1, b1);
    float hi = fmaxf(a1, b1);
    a1 = lo;
    a2 = fminf(hi, fminf(a2, b2));
}
__device__ __forceinline__ void merge2max(float& a1, float& a2, float b1, float b2) {
    float hi = fmaxf(a1, b1);
    float lo = fminf(a1, b1);
    a1 = hi;
    a2 = fmaxf(lo, fmaxf(a2, b2));
}

__global__ __launch_bounds__(NT) void ENCELDDT_fused(
        const float* __restrict__ sigmas,
        const float* __restrict__ y,
        const float* __restrict__ py,
        float* __restrict__ out) {
    __shared__ float wm1[NWAVE], wm2[NWAVE], wM1[NWAVE], wM2[NWAVE];
    __shared__ float s_scal[3];          // m1, begin, interval
    __shared__ float p1[NWAVE], p2[NWAVE], p3[NWAVE];
    __shared__ int   s_cand[MAXC];
    __shared__ int   s_K;

    const int t    = threadIdx.x;
    const int lane = t & 63;
    const int wave = t >> 6;
    if (t == 0) s_K = 0;

    // ---- Phase 1: load 4 sigmas/thread (one pass, kept in registers) ----
    const float4 v4 = reinterpret_cast<const float4*>(sigmas)[t];

    float m1, m2, M1, M2;
    // seed with v4.x, merge the rest
    m1 = v4.x; m2 = INFINITY; M1 = v4.x; M2 = -INFINITY;
    merge2min(m1, m2, v4.y, INFINITY);  merge2max(M1, M2, v4.y, -INFINITY);
    merge2min(m1, m2, v4.z, INFINITY);  merge2max(M1, M2, v4.z, -INFINITY);
    merge2min(m1, m2, v4.w, INFINITY);  merge2max(M1, M2, v4.w, -INFINITY);

    // wave-level butterfly (64 lanes)
    #pragma unroll
    for (int mask = 1; mask < 64; mask <<= 1) {
        float b1 = __shfl_xor(m1, mask);
        float b2 = __shfl_xor(m2, mask);
        merge2min(m1, m2, b1, b2);
        float c1 = __shfl_xor(M1, mask);
        float c2 = __shfl_xor(M2, mask);
        merge2max(M1, M2, c1, c2);
    }
    if (lane == 0) { wm1[wave] = m1; wm2[wave] = m2; wM1[wave] = M1; wM2[wave] = M2; }
    __syncthreads();   // barrier 1 (also covers s_K init)

    if (wave == 0) {
        float a1 = (lane < NWAVE) ? wm1[lane] : INFINITY;
        float a2 = (lane < NWAVE) ? wm2[lane] : INFINITY;
        float c1 = (lane < NWAVE) ? wM1[lane] : -INFINITY;
        float c2 = (lane < NWAVE) ? wM2[lane] : -INFINITY;
        #pragma unroll
        for (int mask = 1; mask < 64; mask <<= 1) {
            float b1 = __shfl_xor(a1, mask);
            float b2 = __shfl_xor(a2, mask);
            merge2min(a1, a2, b1, b2);
            float d1 = __shfl_xor(c1, mask);
            float d2 = __shfl_xor(c2, mask);
            merge2max(c1, c2, d1, d2);
        }
        if (lane == 0) {
            // sig2 strictly decreasing in sigma sum:
            float begin    = sig2_of_sum(c1 + c2);   // min of sig2 (max sums)
            float endv     = sig2_of_sum(a1 + a2);   // max of sig2 (min sums)
            float interval = (endv - begin) / 10.0f;
            s_scal[0] = a1;        // global min sigma
            s_scal[1] = begin;
            s_scal[2] = interval;
        }
    }
    __syncthreads();   // barrier 2

    const float gm1      = s_scal[0];
    const float begin    = s_scal[1];
    const float interval = s_scal[2];

    // ---- Phase 2: candidate test on the 4 register-held values ----
    // i can be in a bin-9 pair only if its best partner (global min sigma)
    // reaches bin 9 (with slack). Exact membership re-tested per pair.
    {
        float vs[4] = {v4.x, v4.y, v4.z, v4.w};
        #pragma unroll
        for (int q = 0; q < 4; ++q) {
            float x = (sig2_of_sum(vs[q] + gm1) - begin) / interval;
            if (x >= 9.0f - 1e-3f) {
                int k = atomicAdd(&s_K, 1);
                if (k < MAXC) s_cand[k] = 4 * t + q;
            }
        }
    }
    __syncthreads();   // barrier 3

    const int K = (s_K < MAXC) ? s_K : MAXC;

    // ---- Phase 3: exact pair loop over K*K ordered pairs ----
    float ssig2 = 0.0f, str2 = 0.0f, cntf = 0.0f;
    const int total = K * K;
    for (int idx = t; idx < total; idx += NT) {
        int a = idx / K;
        int b = idx - a * K;
        if (a == b) continue;          // off-diagonal: i != j
        int i = s_cand[a];
        int j = s_cand[b];

        float s2 = sig2_of_sum(sigmas[i] + sigmas[j]);
        float x  = (s2 - begin) / interval;
        // bin = clip(floor(x),0,9); membership in bin 9 <=> x >= 9.0f
        if (x >= 9.0f) {
            float dx = y[3 * i]     - y[3 * j];
            float dy = y[3 * i + 1] - y[3 * j + 1];
            float dz = y[3 * i + 2] - y[3 * j + 2];
            float dgt = sqrtf((dx * dx + dy * dy) + dz * dz);
            dx = py[3 * i]     - py[3 * j];
            dy = py[3 * i + 1] - py[3 * j + 1];
            dz = py[3 * i + 2] - py[3 * j + 2];
            float dpd = sqrtf((dx * dx + dy * dy) + dz * dz);
            float tr = dgt - dpd;
            ssig2 += s2;
            str2  += tr * tr;
            cntf  += 1.0f;
        }
    }

    // wave butterfly sum
    #pragma unroll
    for (int mask = 1; mask < 64; mask <<= 1) {
        ssig2 += __shfl_xor(ssig2, mask);
        str2  += __shfl_xor(str2,  mask);
        cntf  += __shfl_xor(cntf,  mask);
    }
    if (lane == 0) { p1[wave] = ssig2; p2[wave] = str2; p3[wave] = cntf; }
    __syncthreads();   // barrier 4

    if (wave == 0) {
        float a = (lane < NWAVE) ? p1[lane] : 0.0f;
        float b = (lane < NWAVE) ? p2[lane] : 0.0f;
        float c = (lane < NWAVE) ? p3[lane] : 0.0f;
        #pragma unroll
        for (int mask = 1; mask < 64; mask <<= 1) {
            a += __shfl_xor(a, mask);
            b += __shfl_xor(b, mask);
            c += __shfl_xor(c, mask);
        }
        if (lane == 0) {
            float mvar = sqrtf(a / c);
            float rmse = sqrtf(b / c);
            out[0] = fabsf(mvar - rmse) / mvar;
        }
    }
}

extern "C" void kernel_launch(void* const* d_in, const int* in_sizes, int n_in,
                              void* d_out, int out_size, void* d_ws, size_t ws_size,
                              hipStream_t stream) {
    const float* sigmas = (const float*)d_in[0];
    const float* y      = (const float*)d_in[1];
    const float* py     = (const float*)d_in[2];
    float* out = (float*)d_out;

    ENCELDDT_fused<<<1, NT, 0, stream>>>(sigmas, y, py, out);
}